// Round 6
// baseline (5815.650 us; speedup 1.0000x reference)
//
#include <hip/hip_runtime.h>
#include <hip/hip_bf16.h>
#include <cmath>

// Problem dims
#define Bb 128
#define Tt 512
#define Ii 512
#define Hh 2048
#define Oo 512
#define REC_GRID 256

typedef __bf16 bf16_t;
typedef __bf16 bf16x8 __attribute__((ext_vector_type(8)));
typedef __bf16 bf16x4 __attribute__((ext_vector_type(4)));
typedef float  f32x4_t __attribute__((ext_vector_type(4)));
typedef unsigned long long u64;

static __device__ __forceinline__ bf16_t to_b(float v){ return (bf16_t)v; }
static __device__ __forceinline__ float  b2f(unsigned short u){ unsigned x = ((unsigned)u)<<16; return __builtin_bit_cast(float, x); }
static __device__ __forceinline__ unsigned short f2bbits(float v){ return __builtin_bit_cast(unsigned short, to_b(v)); }

// ---------- small prep kernels ----------
__global__ __launch_bounds__(256) void k_f2b(bf16_t* __restrict__ dst, const float* __restrict__ src){
  size_t i = ((size_t)blockIdx.x*256 + threadIdx.x)*4;
  float4 v = *(const float4*)(src + i);
  bf16x4 o; o[0]=to_b(v.x); o[1]=to_b(v.y); o[2]=to_b(v.z); o[3]=to_b(v.w);
  *(bf16x4*)(dst + i) = o;
}

__global__ __launch_bounds__(256) void k_init_h0(const float* __restrict__ hi_w, const float* __restrict__ hi_b,
                                                 bf16_t* __restrict__ h0b){
  int i = blockIdx.x*256 + threadIdx.x;           // [0, H)
  bf16_t vb = to_b(hi_w[i] + hi_b[i]);
  for (int b=0;b<Bb;++b) h0b[(size_t)b*Hh + i] = vb;
}

__global__ __launch_bounds__(256) void k_convert_x(const float* __restrict__ x, bf16_t* __restrict__ x_tm){
  size_t idx = ((size_t)blockIdx.x*256 + threadIdx.x)*8;
  int    i0  = (int)(idx % Ii);
  size_t m   = idx / Ii;                          // m = t*B + b
  int    t   = (int)(m / Bb), b = (int)(m % Bb);
  const float* s = x + ((size_t)b*Tt + t)*Ii + i0;
  float4 v0 = *(const float4*)s, v1 = *(const float4*)(s+4);
  bf16x8 o;
  o[0]=to_b(v0.x); o[1]=to_b(v0.y); o[2]=to_b(v0.z); o[3]=to_b(v0.w);
  o[4]=to_b(v1.x); o[5]=to_b(v1.y); o[6]=to_b(v1.z); o[7]=to_b(v1.w);
  *(bf16x8*)(x_tm + idx) = o;
}

// ---------- GEMM building blocks (encoder / decoder) ----------
template<int ROWS, int KB>
static __device__ __forceinline__ void stage(const bf16_t* __restrict__ g, long ld, long row0, int k0,
                                             char* __restrict__ ldsT){
  constexpr int SLOTS = KB/8;
  constexpr int PT    = ROWS*SLOTS/256;
  #pragma unroll
  for (int j=0;j<PT;++j){
    int c    = threadIdx.x + 256*j;
    int row  = c / SLOTS, slot = c % SLOTS;
    uint4 v  = *(const uint4*)(g + (row0+row)*ld + k0 + slot*8);
    *(uint4*)(ldsT + row*(KB*2) + ((slot*16) ^ ((row&7)<<4))) = v;
  }
}

template<int KB>
static __device__ __forceinline__ bf16x8 frag(const char* __restrict__ ldsT, int row, int kk, int lane){
  int kbyte = kk*64 + ((lane>>4)<<4);
  return *(const bf16x8*)(ldsT + row*(KB*2) + (kbyte ^ ((row&7)<<4)));
}

template<int EPI>
__global__ __launch_bounds__(256) void gemm128(const bf16_t* __restrict__ A, long lda,
                                               const bf16_t* __restrict__ Bw, long ldb,
                                               const float* __restrict__ bias,
                                               void* __restrict__ Cout, long ldc, int K){
  constexpr int TM=128, TN=128, KB=64;
  __shared__ char lds[(TM+TN)*KB*2];
  char* ldsA = lds;
  char* ldsB = lds + TM*KB*2;
  long m0 = (long)blockIdx.x * TM;
  long n0 = (long)blockIdx.y * TN;
  int w = threadIdx.x >> 6, lane = threadIdx.x & 63;
  int wm = w >> 1, wn = w & 1;
  f32x4_t acc[4][4] = {};
  for (int k0=0;k0<K;k0+=KB){
    __syncthreads();
    stage<TM,KB>(A,  lda, m0, k0, ldsA);
    stage<TN,KB>(Bw, ldb, n0, k0, ldsB);
    __syncthreads();
    #pragma unroll
    for (int kk=0;kk<KB/32;++kk){
      bf16x8 af[4], bfv[4];
      #pragma unroll
      for (int f=0;f<4;++f){ int r = wm*64 + f*16 + (lane&15); af[f]  = frag<KB>(ldsA, r, kk, lane); }
      #pragma unroll
      for (int f=0;f<4;++f){ int r = wn*64 + f*16 + (lane&15); bfv[f] = frag<KB>(ldsB, r, kk, lane); }
      #pragma unroll
      for (int i=0;i<4;++i)
        #pragma unroll
        for (int j=0;j<4;++j)
          acc[i][j] = __builtin_amdgcn_mfma_f32_16x16x32_bf16(af[i], bfv[j], acc[i][j], 0,0,0);
    }
  }
  #pragma unroll
  for (int i=0;i<4;++i)
    #pragma unroll
    for (int j=0;j<4;++j)
      #pragma unroll
      for (int e=0;e<4;++e){
        long row = m0 + wm*64 + i*16 + ((lane>>4)<<2) + e;
        long col = n0 + wn*64 + j*16 + (lane&15);
        float v = acc[i][j][e] + bias[col];
        if (EPI==0) ((bf16_t*)Cout)[row*ldc + col] = to_b(v);
        else        ((float*) Cout)[row*ldc + col] = v;
      }
}

// ---------- persistent recurrence kernel ----------
// 4 groups of 64 blocks; block (g,n): batches 32g..+31, H-cols 32n..+31.
// Wave w = (bh=w&1, kh=w>>1): computes batches [bh*16,+16) x all 32 cols over
// K-half [kh*1024,+1024).  W col-half 0 for its K-half lives in 128 VGPRs
// (loaded once); W col-half 1 in LDS fragment order (uniform+lane*16 reads).
// A (h_prev) fragments are read DIRECTLY from global (L2/MALL) -- 32
// independent dwordx4 loads per wave per step, no LDS staging, no chunk syncs.
// Cross-wave K-reduction via 8 KB LDS. Sync: per-(group,step,K-half) counter;
// producers never wait (per-wave vmcnt + atomicAdd, target 128); consumer
// waves poll only the half-counter they read.
__global__ __launch_bounds__(256, 1) void rec_persist(
    const bf16_t* __restrict__ h0b, const bf16_t* __restrict__ W,
    bf16_t* __restrict__ EH, float* __restrict__ hfinal,
    const float* __restrict__ rec_b, const float* __restrict__ hi_w, const float* __restrict__ hi_b,
    const float* __restrict__ dtp, const float* __restrict__ ap,
    unsigned* __restrict__ cnt)
{
  __shared__ uint4 lds4[75776/16];       // 64K W(ch=1) + 8K reduce + 2K exchange
  char* Wb  = (char*)lds4;
  char* red = (char*)lds4 + 65536;
  u64*  xb  = (u64*)((char*)lds4 + 65536 + 8192);

  const int bid = blockIdx.x;
  const int g   = bid & 3;               // batch group (clusters on XCD pairs)
  const int n   = bid >> 2;              // H tile 0..63
  const int m0  = g * 32;
  const int n0  = n * 32;
  const int khp = (n >> 5);              // which K-half this block's cols feed
  const int tid = threadIdx.x, w = tid >> 6, lane = tid & 63;
  const int bh = w & 1, kh = w >> 1;

  // one-time: W col-half 1 -> LDS in fragment order (16B chunk (kkg,lane))
  for (int it = 0; it < 16; ++it){
    int cid = it*256 + tid;              // 4096 chunks
    int lc  = cid & 63, kkg = cid >> 6;  // kkg 0..63
    uint4 v = *(const uint4*)(W + (size_t)(n0 + 16 + (lc&15))*Hh + kkg*32 + ((lc>>4)<<3));
    *(uint4*)(Wb + (size_t)cid*16) = v;
  }
  // one-time: W col-half 0, this wave's K-half -> 128 VGPRs
  bf16x8 wreg[32];
  {
    const bf16_t* wsrc = W + (size_t)(n0 + (lane&15))*Hh + kh*1024 + ((lane>>4)<<3);
    #pragma unroll
    for (int kk=0;kk<32;++kk) wreg[kk] = *(const bf16x8*)(wsrc + kk*32);
  }
  __syncthreads();

  const float s  = 1.f/(1.f + __expf(-dtp[0]));
  const float av = ap[0];
  const int   batch = m0 + bh*16 + (lane & 15);         // C col = lane&15 -> batch
  const int   hcol0 = n0 + (w>>1)*16 + ((lane>>4)<<2);  // owner cols (ch = w>>1)
  const int   lslot = (bh*16 + (lane & 15))*8 + (w>>1)*4 + (lane>>4);
  float rb[4], hm[4];
  #pragma unroll
  for (int e=0;e<4;++e){ rb[e] = rec_b[hcol0+e]; hm[e] = hi_w[hcol0+e] + hi_b[hcol0+e]; }

  // cooperative enc/h addressing (thread tid -> batch tid>>3, 4-col block tid&7)
  const int co_b = m0 + (tid >> 3);
  const int co_c = n0 + (tid & 7)*4;

  for (int t = 0; t < Tt; ++t){
    // consumer wait: this wave reads h_{t-1} K-half kh (written by 32 blocks x 4 waves)
    if (t){
      const unsigned* cp = cnt + ((unsigned)(g*512 + (t-1))*2) + kh;
      while (__hip_atomic_load(cp, __ATOMIC_RELAXED, __HIP_MEMORY_SCOPE_AGENT) < 128u) {}
    }
    const bf16_t* Asrc = (t==0) ? h0b : (EH + (size_t)(t-1)*(Bb*Hh));
    bf16_t* EHt = EH + (size_t)t*(Bb*Hh);

    // enc for this thread's cooperative slot (own tile, uncached agent load)
    u64 ecv = __hip_atomic_load((const u64*)(EHt + (size_t)co_b*Hh + co_c),
                                __ATOMIC_RELAXED, __HIP_MEMORY_SCOPE_AGENT);

    // K-loop: direct-from-global A frags, reg W (ch0) + LDS W (ch1)
    const bf16_t* hrow = Asrc + (size_t)(m0 + bh*16 + (lane&15))*Hh + kh*1024 + ((lane>>4)<<3);
    const char*   wlb  = Wb + ((size_t)(kh*32)*64 + lane)*16;
    f32x4_t acc0 = {0.f,0.f,0.f,0.f}, acc1 = acc0;
    #pragma unroll
    for (int kk=0;kk<32;++kk){
      bf16x8 hf = *(const bf16x8*)(hrow + kk*32);
      acc0 = __builtin_amdgcn_mfma_f32_16x16x32_bf16(wreg[kk], hf, acc0, 0,0,0);
      bf16x8 wl = *(const bf16x8*)(wlb + kk*1024);
      acc1 = __builtin_amdgcn_mfma_f32_16x16x32_bf16(wl, hf, acc1, 0,0,0);
    }

    // cross-wave K-reduction (wave w owns quadrant bh=w&1, ch=w>>1)
    __syncthreads();                     // prev-iter xb/red readers are done
    *(f32x4_t*)(red + ((w*2+0)*64 + lane)*16) = acc0;
    *(f32x4_t*)(red + ((w*2+1)*64 + lane)*16) = acc1;
    xb[tid] = ecv;
    __syncthreads();
    const int s0 = ((w&1)*2 + (w>>1))*64 + lane;
    f32x4_t fa = *(const f32x4_t*)(red + s0*16) + *(const f32x4_t*)(red + s0*16 + 4096);

    u64 ev = xb[lslot];
    u64 ov = 0;
    #pragma unroll
    for (int e=0;e<4;++e){
      float enc = b2f((unsigned short)(ev >> (16*e)));
      float pre = enc + av*(fa[e] + rb[e]);
      float th  = 1.f - 2.f/(__expf(2.f*pre) + 1.f);   // tanh
      hm[e] = (1.f - s)*hm[e] + s*th;
      ov |= ((u64)f2bbits(hm[e])) << (16*e);
    }
    xb[lslot] = ov;                      // same thread reads then writes its own slot
    __syncthreads();
    u64 hv = xb[tid];
    __hip_atomic_store((u64*)(EHt + (size_t)co_b*Hh + co_c), hv,
                       __ATOMIC_RELAXED, __HIP_MEMORY_SCOPE_AGENT);
    // per-wave completion signal: drain our stores, lane0 bumps this step's counter
    asm volatile("s_waitcnt vmcnt(0)" ::: "memory");
    if ((tid & 63) == 0)
      __hip_atomic_fetch_add(cnt + ((unsigned)(g*512 + t)*2) + khp, 1u,
                             __ATOMIC_RELAXED, __HIP_MEMORY_SCOPE_AGENT);
  }

  // final hidden (f32) -> out tail
  #pragma unroll
  for (int e=0;e<4;++e) hfinal[(size_t)batch*Hh + hcol0 + e] = hm[e];
}

// ---------- launch ----------
extern "C" void kernel_launch(void* const* d_in, const int* in_sizes, int n_in,
                              void* d_out, int out_size, void* d_ws, size_t ws_size,
                              hipStream_t stream){
  const float* x     = (const float*)d_in[0];
  const float* dt    = (const float*)d_in[1];
  const float* a     = (const float*)d_in[2];
  const float* enc_w = (const float*)d_in[3];
  const float* enc_b = (const float*)d_in[4];
  const float* rec_w = (const float*)d_in[5];
  const float* rec_b = (const float*)d_in[6];
  const float* dec_w = (const float*)d_in[7];
  const float* dec_b = (const float*)d_in[8];
  const float* hi_w  = (const float*)d_in[9];
  const float* hi_b  = (const float*)d_in[10];
  float* out = (float*)d_out;

  // workspace carve-out (~333 MB)
  char* ws = (char*)d_ws;
  size_t off = 0;
  auto carve = [&](size_t bytes)->char*{ char* p = ws + off; off += (bytes + 255) & ~(size_t)255; return p; };
  bf16_t* x_tm   = (bf16_t*)carve((size_t)Tt*Bb*Ii*2);   // 64 MB
  bf16_t* EH     = (bf16_t*)carve((size_t)Tt*Bb*Hh*2);   // 256 MB  enc -> h history
  bf16_t* h0b    = (bf16_t*)carve((size_t)Bb*Hh*2);
  bf16_t* enc_wb = (bf16_t*)carve((size_t)Hh*Ii*2);
  bf16_t* rec_wb = (bf16_t*)carve((size_t)Hh*Hh*2);
  bf16_t* dec_wb = (bf16_t*)carve((size_t)Oo*Hh*2);
  unsigned* cnt  = (unsigned*)carve(4*512*2*4);           // per-(group,step,K-half)
  if (off > ws_size) return;  // diagnostic: leaves output zeroed

  // reset barrier counters every call (ws is not re-poisoned between replays)
  hipMemsetAsync(cnt, 0, 4*512*2*4, stream);

  // weights -> bf16
  k_f2b<<<(Hh*Ii)/1024, 256, 0, stream>>>(enc_wb, enc_w);
  k_f2b<<<(Hh*Hh)/1024, 256, 0, stream>>>(rec_wb, rec_w);
  k_f2b<<<(Oo*Hh)/1024, 256, 0, stream>>>(dec_wb, dec_w);
  k_init_h0<<<Hh/256, 256, 0, stream>>>(hi_w, hi_b, h0b);
  k_convert_x<<<((size_t)Tt*Bb*Ii/8)/256, 256, 0, stream>>>(x, x_tm);

  // encoder: EH[t*B+b, h] = x_tm @ enc_w^T + enc_b   (M=65536, K=512, N=2048)
  gemm128<0><<<dim3((Tt*Bb)/128, Hh/128), 256, 0, stream>>>(x_tm, Ii, enc_wb, Ii, enc_b, EH, Hh, Ii);

  // recurrence: one persistent cooperative kernel, 512 steps, half-K counters
  {
    float* hfinal = out + (size_t)Tt*Bb*Oo;
    void* args[] = { (void*)&h0b, (void*)&rec_wb, (void*)&EH, (void*)&hfinal,
                     (void*)&rec_b, (void*)&hi_w, (void*)&hi_b, (void*)&dt, (void*)&a,
                     (void*)&cnt };
    hipLaunchCooperativeKernel((const void*)rec_persist, dim3(REC_GRID), dim3(256), args, 0, stream);
  }

  // decoder: out[t*B+b, o] = EH @ dec_w^T + dec_b   (M=65536, K=2048, N=512)
  gemm128<1><<<dim3((Tt*Bb)/128, Oo/128), 256, 0, stream>>>(EH, Hh, dec_wb, Hh, dec_b, out, Oo, Hh);
}

// Round 9
// 4226.003 us; speedup vs baseline: 1.3762x; 1.3762x over previous
//
#include <hip/hip_runtime.h>
#include <hip/hip_bf16.h>
#include <cmath>

// Problem dims
#define Bb 128
#define Tt 512
#define Ii 512
#define Hh 2048
#define Oo 512
#define REC_GRID 256

typedef __bf16 bf16_t;
typedef __bf16 bf16x8 __attribute__((ext_vector_type(8)));
typedef __bf16 bf16x4 __attribute__((ext_vector_type(4)));
typedef float  f32x4_t __attribute__((ext_vector_type(4)));
typedef unsigned long long u64;

static __device__ __forceinline__ bf16_t to_b(float v){ return (bf16_t)v; }
static __device__ __forceinline__ float  b2f(unsigned short u){ unsigned x = ((unsigned)u)<<16; return __builtin_bit_cast(float, x); }
static __device__ __forceinline__ unsigned short f2bbits(float v){ return __builtin_bit_cast(unsigned short, to_b(v)); }

// ---------- small prep kernels ----------
__global__ __launch_bounds__(256) void k_f2b(bf16_t* __restrict__ dst, const float* __restrict__ src){
  size_t i = ((size_t)blockIdx.x*256 + threadIdx.x)*4;
  float4 v = *(const float4*)(src + i);
  bf16x4 o; o[0]=to_b(v.x); o[1]=to_b(v.y); o[2]=to_b(v.z); o[3]=to_b(v.w);
  *(bf16x4*)(dst + i) = o;
}

__global__ __launch_bounds__(256) void k_init_h0(const float* __restrict__ hi_w, const float* __restrict__ hi_b,
                                                 bf16_t* __restrict__ h0b){
  int i = blockIdx.x*256 + threadIdx.x;           // [0, H)
  bf16_t vb = to_b(hi_w[i] + hi_b[i]);
  for (int b=0;b<Bb;++b) h0b[(size_t)b*Hh + i] = vb;
}

__global__ __launch_bounds__(256) void k_convert_x(const float* __restrict__ x, bf16_t* __restrict__ x_tm){
  size_t idx = ((size_t)blockIdx.x*256 + threadIdx.x)*8;
  int    i0  = (int)(idx % Ii);
  size_t m   = idx / Ii;                          // m = t*B + b
  int    t   = (int)(m / Bb), b = (int)(m % Bb);
  const float* s = x + ((size_t)b*Tt + t)*Ii + i0;
  float4 v0 = *(const float4*)s, v1 = *(const float4*)(s+4);
  bf16x8 o;
  o[0]=to_b(v0.x); o[1]=to_b(v0.y); o[2]=to_b(v0.z); o[3]=to_b(v0.w);
  o[4]=to_b(v1.x); o[5]=to_b(v1.y); o[6]=to_b(v1.z); o[7]=to_b(v1.w);
  *(bf16x8*)(x_tm + idx) = o;
}

// ---------- GEMM building blocks (encoder / decoder) ----------
template<int ROWS, int KB>
static __device__ __forceinline__ void stage(const bf16_t* __restrict__ g, long ld, long row0, int k0,
                                             char* __restrict__ ldsT){
  constexpr int SLOTS = KB/8;
  constexpr int PT    = ROWS*SLOTS/256;
  #pragma unroll
  for (int j=0;j<PT;++j){
    int c    = threadIdx.x + 256*j;
    int row  = c / SLOTS, slot = c % SLOTS;
    uint4 v  = *(const uint4*)(g + (row0+row)*ld + k0 + slot*8);
    *(uint4*)(ldsT + row*(KB*2) + ((slot*16) ^ ((row&7)<<4))) = v;
  }
}

template<int KB>
static __device__ __forceinline__ bf16x8 frag(const char* __restrict__ ldsT, int row, int kk, int lane){
  int kbyte = kk*64 + ((lane>>4)<<4);
  return *(const bf16x8*)(ldsT + row*(KB*2) + (kbyte ^ ((row&7)<<4)));
}

template<int EPI>
__global__ __launch_bounds__(256) void gemm128(const bf16_t* __restrict__ A, long lda,
                                               const bf16_t* __restrict__ Bw, long ldb,
                                               const float* __restrict__ bias,
                                               void* __restrict__ Cout, long ldc, int K){
  constexpr int TM=128, TN=128, KB=64;
  __shared__ char lds[(TM+TN)*KB*2];
  char* ldsA = lds;
  char* ldsB = lds + TM*KB*2;
  long m0 = (long)blockIdx.x * TM;
  long n0 = (long)blockIdx.y * TN;
  int w = threadIdx.x >> 6, lane = threadIdx.x & 63;
  int wm = w >> 1, wn = w & 1;
  f32x4_t acc[4][4] = {};
  for (int k0=0;k0<K;k0+=KB){
    __syncthreads();
    stage<TM,KB>(A,  lda, m0, k0, ldsA);
    stage<TN,KB>(Bw, ldb, n0, k0, ldsB);
    __syncthreads();
    #pragma unroll
    for (int kk=0;kk<KB/32;++kk){
      bf16x8 af[4], bfv[4];
      #pragma unroll
      for (int f=0;f<4;++f){ int r = wm*64 + f*16 + (lane&15); af[f]  = frag<KB>(ldsA, r, kk, lane); }
      #pragma unroll
      for (int f=0;f<4;++f){ int r = wn*64 + f*16 + (lane&15); bfv[f] = frag<KB>(ldsB, r, kk, lane); }
      #pragma unroll
      for (int i=0;i<4;++i)
        #pragma unroll
        for (int j=0;j<4;++j)
          acc[i][j] = __builtin_amdgcn_mfma_f32_16x16x32_bf16(af[i], bfv[j], acc[i][j], 0,0,0);
    }
  }
  #pragma unroll
  for (int i=0;i<4;++i)
    #pragma unroll
    for (int j=0;j<4;++j)
      #pragma unroll
      for (int e=0;e<4;++e){
        long row = m0 + wm*64 + i*16 + ((lane>>4)<<2) + e;
        long col = n0 + wn*64 + j*16 + (lane&15);
        float v = acc[i][j][e] + bias[col];
        if (EPI==0) ((bf16_t*)Cout)[row*ldc + col] = to_b(v);
        else        ((float*) Cout)[row*ldc + col] = v;
      }
}

// ---------- persistent recurrence kernel ----------
// R4 skeleton (4 groups x 64 blocks; block (g,n): batches 32g..+31, cols
// 32n..+31; R4's cooperative u64 agent epilogue; R4's per-(group,step)
// atomicAdd counter). Compute waves w=(bh=w&1, kh=w>>1): 16 batches x all 32
// cols x K-half. W lives in LDS in FRAGMENT ORDER (R5's exact one-time stage:
// chunk (c,j,lane) = W[n0+c*16+(lane&15)][j*32+(lane>>4)*8..+8]) -> every W
// read is uniform+lane*16, conflict-free. h_prev frags read DIRECTLY from
// global (R6's exact formula), 32 independent b128 loads/wave issued in one
// volley -> one latency, no staging barriers. 8KB cross-wave K-reduction.
__global__ __launch_bounds__(256, 1) void rec_persist(
    const bf16_t* __restrict__ h0b, const bf16_t* __restrict__ W,
    bf16_t* __restrict__ EH, float* __restrict__ hfinal,
    const float* __restrict__ rec_b, const float* __restrict__ hi_w, const float* __restrict__ hi_b,
    const float* __restrict__ dtp, const float* __restrict__ ap,
    unsigned* __restrict__ cnt)
{
  __shared__ char lds[131072 + 8192 + 2048];   // W frag-order + red + xb
  char* Wb  = lds;
  char* red = lds + 131072;
  u64*  xb  = (u64*)(lds + 131072 + 8192);

  const int bid = blockIdx.x;
  const int g   = bid & 3;               // batch group
  const int n   = bid >> 2;              // H tile 0..63
  const int m0  = g * 32;
  const int n0  = n * 32;
  unsigned* gcnt = cnt + g*512;
  const int tid = threadIdx.x, w = tid >> 6, lane = tid & 63;
  const int bh = w & 1, kh = w >> 1;     // compute-side split

  // one-time W staging in fragment order (R5-proven formula)
  for (int it = 0; it < 32; ++it){
    int cid = it*256 + tid;              // 8192 chunks of 16B
    int lc  = cid & 63, j = (cid >> 6) & 63, c = cid >> 12;
    uint4 v = *(const uint4*)(W + (size_t)(n0 + c*16 + (lc&15))*Hh + j*32 + ((lc>>4)<<3));
    *(uint4*)(Wb + (size_t)cid*16) = v;
  }
  __syncthreads();

  const float s  = 1.f/(1.f + __expf(-dtp[0]));
  const float av = ap[0];
  // output/epilogue mapping (R4-proven): output wave w owns (bh=w&1, c=w>>1)
  const int   batch = m0 + (w&1)*16 + (lane & 15);
  const int   hcol0 = n0 + (w>>1)*16 + ((lane >> 4) << 2);
  const int   lslot = ((w&1)*16 + (lane & 15))*8 + (w>>1)*4 + (lane>>4);
  float rb[4], hm[4];
  #pragma unroll
  for (int e=0;e<4;++e){ rb[e] = rec_b[hcol0+e]; hm[e] = hi_w[hcol0+e] + hi_b[hcol0+e]; }

  // compute-side addressing
  const size_t hoff = (size_t)(m0 + bh*16 + (lane&15))*Hh + kh*1024 + ((lane>>4)<<3); // R6-proven
  const char*  wb0  = Wb + (size_t)(0*64 + kh*32)*1024 + lane*16;   // col group 0
  const char*  wb1  = Wb + (size_t)(1*64 + kh*32)*1024 + lane*16;   // col group 1
  // cooperative enc/h slot (R4-proven): thread tid -> batch tid>>3, 4-col block tid&7
  const int co_b = m0 + (tid >> 3);
  const int co_c = n0 + (tid & 7)*4;

  for (int t = 0; t < Tt; ++t){
    const bf16_t* Asrc = (t==0) ? h0b : (EH + (size_t)(t-1)*(Bb*Hh));
    bf16_t* EHt = EH + (size_t)t*(Bb*Hh);

    // enc for this thread's cooperative slot (uncached agent load)
    u64 ecv = __hip_atomic_load((const u64*)(EHt + (size_t)co_b*Hh + co_c),
                                __ATOMIC_RELAXED, __HIP_MEMORY_SCOPE_AGENT);

    // one volley of 32 independent h-frag loads (direct global, R6 pattern)
    const bf16_t* hsrc = Asrc + hoff;
    bf16x8 ha[32];
    #pragma unroll
    for (int i=0;i<32;++i) ha[i] = *(const bf16x8*)(hsrc + i*32);

    // 64 MFMAs: 2 col groups x 32 ksteps, 4 accumulator chains
    f32x4_t ac[4] = {};
    #pragma unroll
    for (int i=0;i<32;++i){
      bf16x8 w0f = *(const bf16x8*)(wb0 + i*1024);
      ac[i&1]     = __builtin_amdgcn_mfma_f32_16x16x32_bf16(w0f, ha[i], ac[i&1], 0,0,0);
      bf16x8 w1f = *(const bf16x8*)(wb1 + i*1024);
      ac[2+(i&1)] = __builtin_amdgcn_mfma_f32_16x16x32_bf16(w1f, ha[i], ac[2+(i&1)], 0,0,0);
    }
    f32x4_t acc0 = ac[0] + ac[1];        // col group 0, this (bh,kh)
    f32x4_t acc1 = ac[2] + ac[3];        // col group 1, this (bh,kh)

    // cross-wave K-half reduction: slot (bh,kh,c) = ((bh*2+kh)*2+c)
    __syncthreads();                     // prev-iter red/xb readers done
    *(f32x4_t*)(red + (((bh*2 + kh)*2 + 0)*64 + lane)*16) = acc0;
    *(f32x4_t*)(red + (((bh*2 + kh)*2 + 1)*64 + lane)*16) = acc1;
    xb[tid] = ecv;
    __syncthreads();
    const int r0 = (((w&1)*2 + 0)*2 + (w>>1))*64 + lane;   // my (bh, kh=0, c)
    const int r1 = (((w&1)*2 + 1)*2 + (w>>1))*64 + lane;   // my (bh, kh=1, c)
    f32x4_t fa = *(const f32x4_t*)(red + r0*16) + *(const f32x4_t*)(red + r1*16);

    // R4's exact epilogue: enc via xb, gated tanh, pack, cooperative store
    u64 ev = xb[lslot];
    u64 ov = 0;
    #pragma unroll
    for (int e=0;e<4;++e){
      float enc = b2f((unsigned short)(ev >> (16*e)));
      float pre = enc + av*(fa[e] + rb[e]);
      float th  = 1.f - 2.f/(__expf(2.f*pre) + 1.f);   // tanh
      hm[e] = (1.f - s)*hm[e] + s*th;
      ov |= ((u64)f2bbits(hm[e])) << (16*e);
    }
    xb[lslot] = ov;                      // same thread reads then writes its own slot
    __syncthreads();
    u64 hv = xb[tid];
    __hip_atomic_store((u64*)(EHt + (size_t)co_b*Hh + co_c), hv,
                       __ATOMIC_RELAXED, __HIP_MEMORY_SCOPE_AGENT);
    __syncthreads();                     // drains store acks (vmcnt0 before s_barrier)

    // group barrier: one counter per (group, step)  (R4-proven)
    if (tid == 0){
      __hip_atomic_fetch_add(gcnt + t, 1u, __ATOMIC_RELAXED, __HIP_MEMORY_SCOPE_AGENT);
      while (__hip_atomic_load(gcnt + t, __ATOMIC_RELAXED, __HIP_MEMORY_SCOPE_AGENT) < 64u) {}
    }
    __syncthreads();
  }

  // final hidden (f32) -> out tail
  #pragma unroll
  for (int e=0;e<4;++e) hfinal[(size_t)batch*Hh + hcol0 + e] = hm[e];
}

// ---------- launch ----------
extern "C" void kernel_launch(void* const* d_in, const int* in_sizes, int n_in,
                              void* d_out, int out_size, void* d_ws, size_t ws_size,
                              hipStream_t stream){
  const float* x     = (const float*)d_in[0];
  const float* dt    = (const float*)d_in[1];
  const float* a     = (const float*)d_in[2];
  const float* enc_w = (const float*)d_in[3];
  const float* enc_b = (const float*)d_in[4];
  const float* rec_w = (const float*)d_in[5];
  const float* rec_b = (const float*)d_in[6];
  const float* dec_w = (const float*)d_in[7];
  const float* dec_b = (const float*)d_in[8];
  const float* hi_w  = (const float*)d_in[9];
  const float* hi_b  = (const float*)d_in[10];
  float* out = (float*)d_out;

  // workspace carve-out (~333 MB)
  char* ws = (char*)d_ws;
  size_t off = 0;
  auto carve = [&](size_t bytes)->char*{ char* p = ws + off; off += (bytes + 255) & ~(size_t)255; return p; };
  bf16_t* x_tm   = (bf16_t*)carve((size_t)Tt*Bb*Ii*2);   // 64 MB
  bf16_t* EH     = (bf16_t*)carve((size_t)Tt*Bb*Hh*2);   // 256 MB  enc -> h history
  bf16_t* h0b    = (bf16_t*)carve((size_t)Bb*Hh*2);
  bf16_t* enc_wb = (bf16_t*)carve((size_t)Hh*Ii*2);
  bf16_t* rec_wb = (bf16_t*)carve((size_t)Hh*Hh*2);
  bf16_t* dec_wb = (bf16_t*)carve((size_t)Oo*Hh*2);
  unsigned* cnt  = (unsigned*)carve(4*512*4);             // per-(group,step) counters
  if (off > ws_size) return;  // diagnostic: leaves output zeroed

  // reset barrier counters every call (ws is not re-poisoned between replays)
  hipMemsetAsync(cnt, 0, 4*512*4, stream);

  // weights -> bf16
  k_f2b<<<(Hh*Ii)/1024, 256, 0, stream>>>(enc_wb, enc_w);
  k_f2b<<<(Hh*Hh)/1024, 256, 0, stream>>>(rec_wb, rec_w);
  k_f2b<<<(Oo*Hh)/1024, 256, 0, stream>>>(dec_wb, dec_w);
  k_init_h0<<<Hh/256, 256, 0, stream>>>(hi_w, hi_b, h0b);
  k_convert_x<<<((size_t)Tt*Bb*Ii/8)/256, 256, 0, stream>>>(x, x_tm);

  // encoder: EH[t*B+b, h] = x_tm @ enc_w^T + enc_b   (M=65536, K=512, N=2048)
  gemm128<0><<<dim3((Tt*Bb)/128, Hh/128), 256, 0, stream>>>(x_tm, Ii, enc_wb, Ii, enc_b, EH, Hh, Ii);

  // recurrence: one persistent cooperative kernel, 512 steps
  {
    float* hfinal = out + (size_t)Tt*Bb*Oo;
    void* args[] = { (void*)&h0b, (void*)&rec_wb, (void*)&EH, (void*)&hfinal,
                     (void*)&rec_b, (void*)&hi_w, (void*)&hi_b, (void*)&dt, (void*)&a,
                     (void*)&cnt };
    hipLaunchCooperativeKernel((const void*)rec_persist, dim3(REC_GRID), dim3(256), args, 0, stream);
  }

  // decoder: out[t*B+b, o] = EH @ dec_w^T + dec_b   (M=65536, K=2048, N=512)
  gemm128<1><<<dim3((Tt*Bb)/128, Oo/128), 256, 0, stream>>>(EH, Hh, dec_wb, Hh, dec_b, out, Oo, Hh);
}

// Round 10
// 3075.266 us; speedup vs baseline: 1.8911x; 1.3742x over previous
//
#include <hip/hip_runtime.h>
#include <hip/hip_bf16.h>
#include <cmath>

// Problem dims
#define Bb 128
#define Tt 512
#define Ii 512
#define Hh 2048
#define Oo 512
#define REC_GRID 256

typedef __bf16 bf16_t;
typedef __bf16 bf16x8 __attribute__((ext_vector_type(8)));
typedef __bf16 bf16x4 __attribute__((ext_vector_type(4)));
typedef float  f32x4_t __attribute__((ext_vector_type(4)));
typedef unsigned long long u64;

static __device__ __forceinline__ bf16_t to_b(float v){ return (bf16_t)v; }
static __device__ __forceinline__ float  b2f(unsigned short u){ unsigned x = ((unsigned)u)<<16; return __builtin_bit_cast(float, x); }
static __device__ __forceinline__ unsigned short f2bbits(float v){ return __builtin_bit_cast(unsigned short, to_b(v)); }

// async global->LDS, 16B per lane, linear LDS dest (wave-uniform base + lane*16)
static __device__ __forceinline__ void gl_lds16(const void* g, void* l){
  __builtin_amdgcn_global_load_lds((const __attribute__((address_space(1))) void*)g,
                                   (__attribute__((address_space(3))) void*)l, 16, 0, 0);
}

#define REP32(M) M(0)M(1)M(2)M(3)M(4)M(5)M(6)M(7)M(8)M(9)M(10)M(11)M(12)M(13)M(14)M(15) \
                 M(16)M(17)M(18)M(19)M(20)M(21)M(22)M(23)M(24)M(25)M(26)M(27)M(28)M(29)M(30)M(31)

// ---------- small prep kernels ----------
__global__ __launch_bounds__(256) void k_f2b(bf16_t* __restrict__ dst, const float* __restrict__ src){
  size_t i = ((size_t)blockIdx.x*256 + threadIdx.x)*4;
  float4 v = *(const float4*)(src + i);
  bf16x4 o; o[0]=to_b(v.x); o[1]=to_b(v.y); o[2]=to_b(v.z); o[3]=to_b(v.w);
  *(bf16x4*)(dst + i) = o;
}

__global__ __launch_bounds__(256) void k_init_h0(const float* __restrict__ hi_w, const float* __restrict__ hi_b,
                                                 bf16_t* __restrict__ h0b){
  int i = blockIdx.x*256 + threadIdx.x;           // [0, H)
  bf16_t vb = to_b(hi_w[i] + hi_b[i]);
  for (int b=0;b<Bb;++b) h0b[(size_t)b*Hh + i] = vb;
}

__global__ __launch_bounds__(256) void k_convert_x(const float* __restrict__ x, bf16_t* __restrict__ x_tm){
  size_t idx = ((size_t)blockIdx.x*256 + threadIdx.x)*8;
  int    i0  = (int)(idx % Ii);
  size_t m   = idx / Ii;                          // m = t*B + b
  int    t   = (int)(m / Bb), b = (int)(m % Bb);
  const float* s = x + ((size_t)b*Tt + t)*Ii + i0;
  float4 v0 = *(const float4*)s, v1 = *(const float4*)(s+4);
  bf16x8 o;
  o[0]=to_b(v0.x); o[1]=to_b(v0.y); o[2]=to_b(v0.z); o[3]=to_b(v0.w);
  o[4]=to_b(v1.x); o[5]=to_b(v1.y); o[6]=to_b(v1.z); o[7]=to_b(v1.w);
  *(bf16x8*)(x_tm + idx) = o;
}

// ---------- GEMM building blocks (encoder / decoder) ----------
template<int ROWS, int KB>
static __device__ __forceinline__ void stage(const bf16_t* __restrict__ g, long ld, long row0, int k0,
                                             char* __restrict__ ldsT){
  constexpr int SLOTS = KB/8;
  constexpr int PT    = ROWS*SLOTS/256;
  #pragma unroll
  for (int j=0;j<PT;++j){
    int c    = threadIdx.x + 256*j;
    int row  = c / SLOTS, slot = c % SLOTS;
    uint4 v  = *(const uint4*)(g + (row0+row)*ld + k0 + slot*8);
    *(uint4*)(ldsT + row*(KB*2) + ((slot*16) ^ ((row&7)<<4))) = v;
  }
}

template<int KB>
static __device__ __forceinline__ bf16x8 frag(const char* __restrict__ ldsT, int row, int kk, int lane){
  int kbyte = kk*64 + ((lane>>4)<<4);
  return *(const bf16x8*)(ldsT + row*(KB*2) + (kbyte ^ ((row&7)<<4)));
}

template<int EPI>
__global__ __launch_bounds__(256) void gemm128(const bf16_t* __restrict__ A, long lda,
                                               const bf16_t* __restrict__ Bw, long ldb,
                                               const float* __restrict__ bias,
                                               void* __restrict__ Cout, long ldc, int K){
  constexpr int TM=128, TN=128, KB=64;
  __shared__ char lds[(TM+TN)*KB*2];
  char* ldsA = lds;
  char* ldsB = lds + TM*KB*2;
  long m0 = (long)blockIdx.x * TM;
  long n0 = (long)blockIdx.y * TN;
  int w = threadIdx.x >> 6, lane = threadIdx.x & 63;
  int wm = w >> 1, wn = w & 1;
  f32x4_t acc[4][4] = {};
  for (int k0=0;k0<K;k0+=KB){
    __syncthreads();
    stage<TM,KB>(A,  lda, m0, k0, ldsA);
    stage<TN,KB>(Bw, ldb, n0, k0, ldsB);
    __syncthreads();
    #pragma unroll
    for (int kk=0;kk<KB/32;++kk){
      bf16x8 af[4], bfv[4];
      #pragma unroll
      for (int f=0;f<4;++f){ int r = wm*64 + f*16 + (lane&15); af[f]  = frag<KB>(ldsA, r, kk, lane); }
      #pragma unroll
      for (int f=0;f<4;++f){ int r = wn*64 + f*16 + (lane&15); bfv[f] = frag<KB>(ldsB, r, kk, lane); }
      #pragma unroll
      for (int i=0;i<4;++i)
        #pragma unroll
        for (int j=0;j<4;++j)
          acc[i][j] = __builtin_amdgcn_mfma_f32_16x16x32_bf16(af[i], bfv[j], acc[i][j], 0,0,0);
    }
  }
  #pragma unroll
  for (int i=0;i<4;++i)
    #pragma unroll
    for (int j=0;j<4;++j)
      #pragma unroll
      for (int e=0;e<4;++e){
        long row = m0 + wm*64 + i*16 + ((lane>>4)<<2) + e;
        long col = n0 + wn*64 + j*16 + (lane&15);
        float v = acc[i][j][e] + bias[col];
        if (EPI==0) ((bf16_t*)Cout)[row*ldc + col] = to_b(v);
        else        ((float*) Cout)[row*ldc + col] = v;
      }
}

// ---------- persistent recurrence kernel ----------
// 4 groups x 64 blocks; block (g,n): batches 32g..+31, H-cols 32n..+31.
// INIT: W staged to LDS in fragment order (R5/R9-proven formula); each wave
// (ch=w&1, kh=w>>1) ds_reads its 32 fragments (16 cols x K-half) into 32 named
// VGPR vars; then the W LDS region is REUSED as the h volley buffer -- the
// visible aliasing makes W-reload unsound, pinning W in registers (no asm).
// PER STEP: ONE 128KB h volley via global_load_lds (R4's exact stage formula,
// 8 chunks of 16KB issued back-to-back, single barrier); 64 MFMAs per wave
// (2 batch-halves x 32 kk) reading h frags with R4's exact read formula; 8KB
// cross-wave kh-reduction; R4's exact cooperative u64 agent epilogue and
// per-(group,step) counter barrier.
__global__ __launch_bounds__(256, 1) void rec_persist(
    const bf16_t* __restrict__ h0b, const bf16_t* __restrict__ W,
    bf16_t* __restrict__ EH, float* __restrict__ hfinal,
    const float* __restrict__ rec_b, const float* __restrict__ hi_w, const float* __restrict__ hi_b,
    const float* __restrict__ dtp, const float* __restrict__ ap,
    unsigned* __restrict__ cnt)
{
  __shared__ char lds[131072 + 8192 + 2048];   // W-init/h-volley (aliased) + red + xb
  char* Wb   = lds;                            // init only
  char* hbuf = lds;                            // per-step volley (reuses Wb)
  char* red  = lds + 131072;
  u64*  xb   = (u64*)(lds + 131072 + 8192);

  const int bid = blockIdx.x;
  const int g   = bid & 3;               // batch group
  const int n   = bid >> 2;              // H tile 0..63
  const int m0  = g * 32;
  const int n0  = n * 32;
  unsigned* gcnt = cnt + g*512;
  const int tid = threadIdx.x, w = tid >> 6, lane = tid & 63;
  const int l15 = lane & 15, ks16 = (lane >> 4) << 4;
  const int ch = w & 1, kh = w >> 1;     // compute-wave role: col-half, K-half

  // ---- one-time: W -> LDS fragment order (R9-proven), then -> 128 VGPRs ----
  for (int it = 0; it < 32; ++it){
    int cid = it*256 + tid;              // 8192 chunks of 16B
    int lc  = cid & 63, j = (cid >> 6) & 63, c = cid >> 12;
    uint4 v = *(const uint4*)(W + (size_t)(n0 + c*16 + (lc&15))*Hh + j*32 + ((lc>>4)<<3));
    *(uint4*)(Wb + (size_t)cid*16) = v;
  }
  __syncthreads();
  // wave (ch,kh): fragment kk -> chunk (ch*64 + kh*32 + kk, lane)
  const char* wfb = Wb + ((size_t)(ch*64 + kh*32)*64 + lane)*16;
  #define WDECL(i) bf16x8 w##i = *(const bf16x8*)(wfb + (i)*1024);
  REP32(WDECL)
  #undef WDECL
  __syncthreads();                       // all W reads done; LDS reusable as hbuf

  const float s  = 1.f/(1.f + __expf(-dtp[0]));
  const float av = ap[0];
  // output/epilogue mapping (R4-proven): output wave w owns (bh_o=w&1, ch_o=w>>1)
  const int   batch = m0 + (w&1)*16 + l15;
  const int   hcol0 = n0 + (w>>1)*16 + ((lane >> 4) << 2);
  const int   lslot = ((w&1)*16 + l15)*8 + (w>>1)*4 + (lane>>4);
  float rb[4], hm[4];
  #pragma unroll
  for (int e=0;e<4;++e){ rb[e] = rec_b[hcol0+e]; hm[e] = hi_w[hcol0+e] + hi_b[hcol0+e]; }

  // h frag read addressing (R4-proven): row r at r*512, col-byte ^ ((r&7)<<4)
  const int   axor = (l15 & 7) << 4;
  const char* hb0  = hbuf + kh*65536 + (size_t)l15*512;        // bh=0 rows
  const char* hb1  = hb0 + 8192;                               // bh=1 rows (+16*512)
  // staging addressing (R4-proven): wave w stages rows w*8..+7 of each chunk
  const int   srow  = lane >> 5;
  const int   scolx = (lane & 31) << 4;
  // cooperative enc/h slot (R4-proven)
  const int co_b = m0 + (tid >> 3);
  const int co_c = n0 + (tid & 7)*4;

  for (int t = 0; t < Tt; ++t){
    const bf16_t* Asrc = (t==0) ? h0b : (EH + (size_t)(t-1)*(Bb*Hh));
    bf16_t* EHt = EH + (size_t)t*(Bb*Hh);

    // enc for this thread's cooperative slot (uncached agent load; overlaps volley)
    u64 ecv = __hip_atomic_load((const u64*)(EHt + (size_t)co_b*Hh + co_c),
                                __ATOMIC_RELAXED, __HIP_MEMORY_SCOPE_AGENT);

    // ONE volley: all 8 chunks (R4's exact per-chunk formulas), 32 gl_lds/wave
    #pragma unroll
    for (int c = 0; c < 8; ++c){
      char* dst = hbuf + c*16384 + (w<<12);
      const char* asb = (const char*)Asrc + ((size_t)(m0 + w*8 + srow))*(Hh*2) + c*512;
      #pragma unroll
      for (int i = 0; i < 4; ++i){
        int row = w*8 + srow + 2*i;
        int cb  = scolx ^ ((row & 7) << 4);
        gl_lds16(asb + (size_t)(2*i)*(Hh*2) + cb, dst + (i<<10));
      }
    }
    __syncthreads();                     // volley complete (vmcnt drained at barrier)

    // K-loop: 64 MFMAs (2 bh x 32 kk), W from VGPRs, h from hbuf (R4 read formula)
    f32x4_t acc0 = {0.f,0.f,0.f,0.f}, acc1 = acc0;
    #define KSTEP(kk) { \
      int off = (((kk)&7)*64 + ks16) ^ axor; \
      bf16x8 h0v = *(const bf16x8*)(hb0 + ((kk)>>3)*16384 + off); \
      acc0 = __builtin_amdgcn_mfma_f32_16x16x32_bf16(w##kk, h0v, acc0, 0,0,0); \
      bf16x8 h1v = *(const bf16x8*)(hb1 + ((kk)>>3)*16384 + off); \
      acc1 = __builtin_amdgcn_mfma_f32_16x16x32_bf16(w##kk, h1v, acc1, 0,0,0); }
    REP32(KSTEP)
    #undef KSTEP

    // cross-wave kh-reduction: slot (bh*2+ch)*2 + kh
    __syncthreads();                     // all hbuf reads done; red/xb prev readers done
    *(f32x4_t*)(red + (((0*2 + ch)*2 + kh)*64 + lane)*16) = acc0;
    *(f32x4_t*)(red + (((1*2 + ch)*2 + kh)*64 + lane)*16) = acc1;
    xb[tid] = ecv;
    __syncthreads();
    const int r0 = (((w&1)*2 + (w>>1))*2 + 0)*64 + lane;     // my (bh_o, ch_o), kh=0
    const int r1 = (((w&1)*2 + (w>>1))*2 + 1)*64 + lane;     // my (bh_o, ch_o), kh=1
    f32x4_t fa = *(const f32x4_t*)(red + r0*16) + *(const f32x4_t*)(red + r1*16);

    // R4's exact epilogue
    u64 ev = xb[lslot];
    u64 ov = 0;
    #pragma unroll
    for (int e=0;e<4;++e){
      float enc = b2f((unsigned short)(ev >> (16*e)));
      float pre = enc + av*(fa[e] + rb[e]);
      float th  = 1.f - 2.f/(__expf(2.f*pre) + 1.f);   // tanh
      hm[e] = (1.f - s)*hm[e] + s*th;
      ov |= ((u64)f2bbits(hm[e])) << (16*e);
    }
    xb[lslot] = ov;
    __syncthreads();
    u64 hv = xb[tid];
    __hip_atomic_store((u64*)(EHt + (size_t)co_b*Hh + co_c), hv,
                       __ATOMIC_RELAXED, __HIP_MEMORY_SCOPE_AGENT);
    __syncthreads();                     // drains store acks

    // group barrier: one counter per (group, step)  (R4-proven)
    if (tid == 0){
      __hip_atomic_fetch_add(gcnt + t, 1u, __ATOMIC_RELAXED, __HIP_MEMORY_SCOPE_AGENT);
      while (__hip_atomic_load(gcnt + t, __ATOMIC_RELAXED, __HIP_MEMORY_SCOPE_AGENT) < 64u) {}
    }
    __syncthreads();
  }

  // final hidden (f32) -> out tail
  #pragma unroll
  for (int e=0;e<4;++e) hfinal[(size_t)batch*Hh + hcol0 + e] = hm[e];
}

// ---------- launch ----------
extern "C" void kernel_launch(void* const* d_in, const int* in_sizes, int n_in,
                              void* d_out, int out_size, void* d_ws, size_t ws_size,
                              hipStream_t stream){
  const float* x     = (const float*)d_in[0];
  const float* dt    = (const float*)d_in[1];
  const float* a     = (const float*)d_in[2];
  const float* enc_w = (const float*)d_in[3];
  const float* enc_b = (const float*)d_in[4];
  const float* rec_w = (const float*)d_in[5];
  const float* rec_b = (const float*)d_in[6];
  const float* dec_w = (const float*)d_in[7];
  const float* dec_b = (const float*)d_in[8];
  const float* hi_w  = (const float*)d_in[9];
  const float* hi_b  = (const float*)d_in[10];
  float* out = (float*)d_out;

  // workspace carve-out (~333 MB)
  char* ws = (char*)d_ws;
  size_t off = 0;
  auto carve = [&](size_t bytes)->char*{ char* p = ws + off; off += (bytes + 255) & ~(size_t)255; return p; };
  bf16_t* x_tm   = (bf16_t*)carve((size_t)Tt*Bb*Ii*2);   // 64 MB
  bf16_t* EH     = (bf16_t*)carve((size_t)Tt*Bb*Hh*2);   // 256 MB  enc -> h history
  bf16_t* h0b    = (bf16_t*)carve((size_t)Bb*Hh*2);
  bf16_t* enc_wb = (bf16_t*)carve((size_t)Hh*Ii*2);
  bf16_t* rec_wb = (bf16_t*)carve((size_t)Hh*Hh*2);
  bf16_t* dec_wb = (bf16_t*)carve((size_t)Oo*Hh*2);
  unsigned* cnt  = (unsigned*)carve(4*512*4);             // per-(group,step) counters
  if (off > ws_size) return;  // diagnostic: leaves output zeroed

  // reset barrier counters every call (ws is not re-poisoned between replays)
  hipMemsetAsync(cnt, 0, 4*512*4, stream);

  // weights -> bf16
  k_f2b<<<(Hh*Ii)/1024, 256, 0, stream>>>(enc_wb, enc_w);
  k_f2b<<<(Hh*Hh)/1024, 256, 0, stream>>>(rec_wb, rec_w);
  k_f2b<<<(Oo*Hh)/1024, 256, 0, stream>>>(dec_wb, dec_w);
  k_init_h0<<<Hh/256, 256, 0, stream>>>(hi_w, hi_b, h0b);
  k_convert_x<<<((size_t)Tt*Bb*Ii/8)/256, 256, 0, stream>>>(x, x_tm);

  // encoder: EH[t*B+b, h] = x_tm @ enc_w^T + enc_b   (M=65536, K=512, N=2048)
  gemm128<0><<<dim3((Tt*Bb)/128, Hh/128), 256, 0, stream>>>(x_tm, Ii, enc_wb, Ii, enc_b, EH, Hh, Ii);

  // recurrence: one persistent cooperative kernel, 512 steps
  {
    float* hfinal = out + (size_t)Tt*Bb*Oo;
    void* args[] = { (void*)&h0b, (void*)&rec_wb, (void*)&EH, (void*)&hfinal,
                     (void*)&rec_b, (void*)&hi_w, (void*)&hi_b, (void*)&dt, (void*)&a,
                     (void*)&cnt };
    hipLaunchCooperativeKernel((const void*)rec_persist, dim3(REC_GRID), dim3(256), args, 0, stream);
  }

  // decoder: out[t*B+b, o] = EH @ dec_w^T + dec_b   (M=65536, K=2048, N=512)
  gemm128<1><<<dim3((Tt*Bb)/128, Oo/128), 256, 0, stream>>>(EH, Hh, dec_wb, Hh, dec_b, out, Oo, Hh);
}

// Round 11
// 2853.700 us; speedup vs baseline: 2.0379x; 1.0776x over previous
//
#include <hip/hip_runtime.h>
#include <hip/hip_bf16.h>
#include <cmath>

// Problem dims
#define Bb 128
#define Tt 512
#define Ii 512
#define Hh 2048
#define Oo 512
#define REC_GRID 256

typedef __bf16 bf16_t;
typedef __bf16 bf16x8 __attribute__((ext_vector_type(8)));
typedef __bf16 bf16x4 __attribute__((ext_vector_type(4)));
typedef float  f32x4_t __attribute__((ext_vector_type(4)));
typedef unsigned long long u64;
typedef unsigned u32;

static __device__ __forceinline__ bf16_t to_b(float v){ return (bf16_t)v; }
static __device__ __forceinline__ float  b2f(unsigned short u){ unsigned x = ((unsigned)u)<<16; return __builtin_bit_cast(float, x); }
static __device__ __forceinline__ unsigned short f2bbits(float v){ return __builtin_bit_cast(unsigned short, to_b(v)); }

// async global->LDS, 16B per lane, linear LDS dest (wave-uniform base + lane*16)
static __device__ __forceinline__ void gl_lds16(const void* g, void* l){
  __builtin_amdgcn_global_load_lds((const __attribute__((address_space(1))) void*)g,
                                   (__attribute__((address_space(3))) void*)l, 16, 0, 0);
}

#define REP16(M) M(0)M(1)M(2)M(3)M(4)M(5)M(6)M(7)M(8)M(9)M(10)M(11)M(12)M(13)M(14)M(15)

// ---------- small prep kernels ----------
__global__ __launch_bounds__(256) void k_f2b(bf16_t* __restrict__ dst, const float* __restrict__ src){
  size_t i = ((size_t)blockIdx.x*256 + threadIdx.x)*4;
  float4 v = *(const float4*)(src + i);
  bf16x4 o; o[0]=to_b(v.x); o[1]=to_b(v.y); o[2]=to_b(v.z); o[3]=to_b(v.w);
  *(bf16x4*)(dst + i) = o;
}

__global__ __launch_bounds__(256) void k_init_h0(const float* __restrict__ hi_w, const float* __restrict__ hi_b,
                                                 bf16_t* __restrict__ h0b){
  int i = blockIdx.x*256 + threadIdx.x;           // [0, H)
  bf16_t vb = to_b(hi_w[i] + hi_b[i]);
  for (int b=0;b<Bb;++b) h0b[(size_t)b*Hh + i] = vb;
}

__global__ __launch_bounds__(256) void k_convert_x(const float* __restrict__ x, bf16_t* __restrict__ x_tm){
  size_t idx = ((size_t)blockIdx.x*256 + threadIdx.x)*8;
  int    i0  = (int)(idx % Ii);
  size_t m   = idx / Ii;                          // m = t*B + b
  int    t   = (int)(m / Bb), b = (int)(m % Bb);
  const float* s = x + ((size_t)b*Tt + t)*Ii + i0;
  float4 v0 = *(const float4*)s, v1 = *(const float4*)(s+4);
  bf16x8 o;
  o[0]=to_b(v0.x); o[1]=to_b(v0.y); o[2]=to_b(v0.z); o[3]=to_b(v0.w);
  o[4]=to_b(v1.x); o[5]=to_b(v1.y); o[6]=to_b(v1.z); o[7]=to_b(v1.w);
  *(bf16x8*)(x_tm + idx) = o;
}

// ---------- GEMM building blocks (encoder / decoder) ----------
template<int ROWS, int KB>
static __device__ __forceinline__ void stage(const bf16_t* __restrict__ g, long ld, long row0, int k0,
                                             char* __restrict__ ldsT){
  constexpr int SLOTS = KB/8;
  constexpr int PT    = ROWS*SLOTS/256;
  #pragma unroll
  for (int j=0;j<PT;++j){
    int c    = threadIdx.x + 256*j;
    int row  = c / SLOTS, slot = c % SLOTS;
    uint4 v  = *(const uint4*)(g + (row0+row)*ld + k0 + slot*8);
    *(uint4*)(ldsT + row*(KB*2) + ((slot*16) ^ ((row&7)<<4))) = v;
  }
}

template<int KB>
static __device__ __forceinline__ bf16x8 frag(const char* __restrict__ ldsT, int row, int kk, int lane){
  int kbyte = kk*64 + ((lane>>4)<<4);
  return *(const bf16x8*)(ldsT + row*(KB*2) + (kbyte ^ ((row&7)<<4)));
}

template<int EPI>
__global__ __launch_bounds__(256) void gemm128(const bf16_t* __restrict__ A, long lda,
                                               const bf16_t* __restrict__ Bw, long ldb,
                                               const float* __restrict__ bias,
                                               void* __restrict__ Cout, long ldc, int K){
  constexpr int TM=128, TN=128, KB=64;
  __shared__ char lds[(TM+TN)*KB*2];
  char* ldsA = lds;
  char* ldsB = lds + TM*KB*2;
  long m0 = (long)blockIdx.x * TM;
  long n0 = (long)blockIdx.y * TN;
  int w = threadIdx.x >> 6, lane = threadIdx.x & 63;
  int wm = w >> 1, wn = w & 1;
  f32x4_t acc[4][4] = {};
  for (int k0=0;k0<K;k0+=KB){
    __syncthreads();
    stage<TM,KB>(A,  lda, m0, k0, ldsA);
    stage<TN,KB>(Bw, ldb, n0, k0, ldsB);
    __syncthreads();
    #pragma unroll
    for (int kk=0;kk<KB/32;++kk){
      bf16x8 af[4], bfv[4];
      #pragma unroll
      for (int f=0;f<4;++f){ int r = wm*64 + f*16 + (lane&15); af[f]  = frag<KB>(ldsA, r, kk, lane); }
      #pragma unroll
      for (int f=0;f<4;++f){ int r = wn*64 + f*16 + (lane&15); bfv[f] = frag<KB>(ldsB, r, kk, lane); }
      #pragma unroll
      for (int i=0;i<4;++i)
        #pragma unroll
        for (int j=0;j<4;++j)
          acc[i][j] = __builtin_amdgcn_mfma_f32_16x16x32_bf16(af[i], bfv[j], acc[i][j], 0,0,0);
    }
  }
  #pragma unroll
  for (int i=0;i<4;++i)
    #pragma unroll
    for (int j=0;j<4;++j)
      #pragma unroll
      for (int e=0;e<4;++e){
        long row = m0 + wm*64 + i*16 + ((lane>>4)<<2) + e;
        long col = n0 + wn*64 + j*16 + (lane&15);
        float v = acc[i][j][e] + bias[col];
        if (EPI==0) ((bf16_t*)Cout)[row*ldc + col] = to_b(v);
        else        ((float*) Cout)[row*ldc + col] = v;
      }
}

// ---------- persistent recurrence kernel (512 threads / 8 waves) ----------
// 4 groups x 64 blocks; block (g,n): batches 32g..+31, H-cols 32n..+31.
// Compute wave w = (ch=w&1, kq=w>>1 in 0..3): 16 cols x K-quarter x 32 batches.
// INIT: W -> LDS fragment order (R9/R10-proven), each wave ds_reads its 16
// frags (64 VGPRs) into named vars; LDS region then reused as h volley buffer
// (aliasing pins W out of LDS; no asm -- R7/R8's "+v" pin corrupted data).
// PER STEP: ONE 128KB volley (wave w stages chunk w: 16 gl_lds, R10's exact
// stage/read formula pair); 32 MFMAs/wave; 16KB kq-reduction; u32 cooperative
// agent-atomic enc/h exchange; per-(group,step) counter barrier (R4-proven).
__global__ __launch_bounds__(512, 1) void rec_persist(
    const bf16_t* __restrict__ h0b, const bf16_t* __restrict__ W,
    bf16_t* __restrict__ EH, float* __restrict__ hfinal,
    const float* __restrict__ rec_b, const float* __restrict__ hi_w, const float* __restrict__ hi_b,
    const float* __restrict__ dtp, const float* __restrict__ ap,
    unsigned* __restrict__ cnt)
{
  __shared__ char lds[131072 + 16384 + 2048];  // W-init/h-volley (aliased) + red + xb
  char* Wb   = lds;                            // init only
  char* hbuf = lds;                            // per-step volley (reuses Wb)
  char* red  = lds + 131072;
  u32*  xb   = (u32*)(lds + 131072 + 16384);

  const int bid = blockIdx.x;
  const int g   = bid & 3;               // batch group
  const int n   = bid >> 2;              // H tile 0..63
  const int m0  = g * 32;
  const int n0  = n * 32;
  unsigned* gcnt = cnt + g*512;
  const int tid = threadIdx.x, w = tid >> 6, lane = tid & 63;
  const int l15 = lane & 15, ks16 = (lane >> 4) << 4;
  const int ch = w & 1, kq = w >> 1;     // compute role: col-half, K-quarter

  // ---- one-time: W -> LDS fragment order (proven formula), then 16 frags -> VGPRs
  for (int it = 0; it < 16; ++it){
    int cid = it*512 + tid;              // 8192 chunks of 16B
    int lc  = cid & 63, j = (cid >> 6) & 63, c = cid >> 12;
    uint4 v = *(const uint4*)(W + (size_t)(n0 + c*16 + (lc&15))*Hh + j*32 + ((lc>>4)<<3));
    *(uint4*)(Wb + (size_t)cid*16) = v;
  }
  __syncthreads();
  // wave (ch,kq): global kk = kq*16 + i -> chunk ch*64 + kq*16 + i
  const char* wfb = Wb + ((size_t)(ch*64 + kq*16)*64 + lane)*16;
  #define WDECL(i) bf16x8 w##i = *(const bf16x8*)(wfb + (i)*1024);
  REP16(WDECL)
  #undef WDECL
  __syncthreads();                       // all W reads done; LDS reusable as hbuf

  const float s  = 1.f/(1.f + __expf(-dtp[0]));
  const float av = ap[0];
  // output/epilogue role: bh_o = w&1, ch_o = (w>>1)&1, eh = w>>2 (e-pair)
  const int   bh_o = w & 1, ch_o = (w >> 1) & 1, eh = w >> 2;
  const int   batch = m0 + bh_o*16 + l15;
  const int   hcol0 = n0 + ch_o*16 + ((lane >> 4) << 2) + eh*2;   // 2 cols/thread
  const int   lslot = (bh_o*16 + l15)*16 + ch_o*8 + (lane>>4)*2 + eh;
  float rb[2], hm[2];
  #pragma unroll
  for (int e=0;e<2;++e){ rb[e] = rec_b[hcol0+e]; hm[e] = hi_w[hcol0+e] + hi_b[hcol0+e]; }

  // h frag read addressing (R10-proven): row r at r*512, col-byte ^ ((r&7)<<4)
  const int   axor = (l15 & 7) << 4;
  const char* hb0  = hbuf + kq*32768 + (size_t)l15*512;   // bh=0 rows
  const char* hb1  = hb0 + 8192;                          // bh=1 rows (+16*512)
  // staging (R10-proven formulas): wave w stages chunk c=w (all 32 rows x 512B)
  const int   srow  = lane >> 5;
  const int   scolx = (lane & 31) << 4;
  // cooperative enc/h slot: thread tid -> batch tid>>4, col pair tid&15
  const int co_b = m0 + (tid >> 4);
  const int co_c = n0 + (tid & 15)*2;

  for (int t = 0; t < Tt; ++t){
    const bf16_t* Asrc = (t==0) ? h0b : (EH + (size_t)(t-1)*(Bb*Hh));
    bf16_t* EHt = EH + (size_t)t*(Bb*Hh);

    // enc for this thread's cooperative slot (uncached agent load; overlaps volley)
    u32 ecv = __hip_atomic_load((const u32*)(EHt + (size_t)co_b*Hh + co_c),
                                __ATOMIC_RELAXED, __HIP_MEMORY_SCOPE_AGENT);

    // ONE volley: wave w stages chunk w (rows 2i+srow, 16 gl_lds)
    {
      char* dst = hbuf + w*16384;
      const char* asb = (const char*)Asrc + ((size_t)(m0 + srow))*(Hh*2) + w*512;
      #pragma unroll
      for (int i = 0; i < 16; ++i){
        int row = 2*i + srow;
        int cb  = scolx ^ ((row & 7) << 4);
        gl_lds16(asb + (size_t)(2*i)*(Hh*2) + cb, dst + (i<<10));
      }
    }
    __syncthreads();                     // volley complete (vmcnt drained at barrier)

    // K-loop: 32 MFMAs (2 bh x 16 kk), W from VGPRs, h from hbuf (R10 read formula)
    f32x4_t acc0 = {0.f,0.f,0.f,0.f}, acc1 = acc0;
    #define KSTEP(kk) { \
      int off = ((kk)>>3)*16384 + ((((kk)&7)*64 + ks16) ^ axor); \
      bf16x8 h0v = *(const bf16x8*)(hb0 + off); \
      acc0 = __builtin_amdgcn_mfma_f32_16x16x32_bf16(w##kk, h0v, acc0, 0,0,0); \
      bf16x8 h1v = *(const bf16x8*)(hb1 + off); \
      acc1 = __builtin_amdgcn_mfma_f32_16x16x32_bf16(w##kk, h1v, acc1, 0,0,0); }
    REP16(KSTEP)
    #undef KSTEP

    // cross-wave kq-reduction: slot (bh*2 + ch)*4 + kq
    __syncthreads();                     // all hbuf reads done; prev red/xb readers done
    *(f32x4_t*)(red + (((0*2 + ch)*4 + kq)*64 + lane)*16) = acc0;
    *(f32x4_t*)(red + (((1*2 + ch)*4 + kq)*64 + lane)*16) = acc1;
    xb[tid] = ecv;
    __syncthreads();
    const int rbase = ((bh_o*2 + ch_o)*4)*64 + lane;
    f32x4_t fa = *(const f32x4_t*)(red + rbase*16);
    #pragma unroll
    for (int q=1;q<4;++q) fa = fa + *(const f32x4_t*)(red + (rbase + q*64)*16);

    // epilogue: 2 cols/thread, u32 exchange, cooperative agent store
    u32 ev = xb[lslot];
    u32 ov = 0;
    #pragma unroll
    for (int e=0;e<2;++e){
      float enc = b2f((unsigned short)(ev >> (16*e)));
      float pre = enc + av*(fa[eh*2+e] + rb[e]);
      float th  = 1.f - 2.f/(__expf(2.f*pre) + 1.f);   // tanh
      hm[e] = (1.f - s)*hm[e] + s*th;
      ov |= ((u32)f2bbits(hm[e])) << (16*e);
    }
    xb[lslot] = ov;                      // same thread reads then writes its own slot
    __syncthreads();
    u32 hv = xb[tid];
    __hip_atomic_store((u32*)(EHt + (size_t)co_b*Hh + co_c), hv,
                       __ATOMIC_RELAXED, __HIP_MEMORY_SCOPE_AGENT);
    __syncthreads();                     // drains store acks (vmcnt0 before s_barrier)

    // group barrier: one counter per (group, step)  (R4-proven)
    if (tid == 0){
      __hip_atomic_fetch_add(gcnt + t, 1u, __ATOMIC_RELAXED, __HIP_MEMORY_SCOPE_AGENT);
      while (__hip_atomic_load(gcnt + t, __ATOMIC_RELAXED, __HIP_MEMORY_SCOPE_AGENT) < 64u) {}
    }
    __syncthreads();
  }

  // final hidden (f32) -> out tail
  #pragma unroll
  for (int e=0;e<2;++e) hfinal[(size_t)batch*Hh + hcol0 + e] = hm[e];
}

// ---------- launch ----------
extern "C" void kernel_launch(void* const* d_in, const int* in_sizes, int n_in,
                              void* d_out, int out_size, void* d_ws, size_t ws_size,
                              hipStream_t stream){
  const float* x     = (const float*)d_in[0];
  const float* dt    = (const float*)d_in[1];
  const float* a     = (const float*)d_in[2];
  const float* enc_w = (const float*)d_in[3];
  const float* enc_b = (const float*)d_in[4];
  const float* rec_w = (const float*)d_in[5];
  const float* rec_b = (const float*)d_in[6];
  const float* dec_w = (const float*)d_in[7];
  const float* dec_b = (const float*)d_in[8];
  const float* hi_w  = (const float*)d_in[9];
  const float* hi_b  = (const float*)d_in[10];
  float* out = (float*)d_out;

  // workspace carve-out (~333 MB)
  char* ws = (char*)d_ws;
  size_t off = 0;
  auto carve = [&](size_t bytes)->char*{ char* p = ws + off; off += (bytes + 255) & ~(size_t)255; return p; };
  bf16_t* x_tm   = (bf16_t*)carve((size_t)Tt*Bb*Ii*2);   // 64 MB
  bf16_t* EH     = (bf16_t*)carve((size_t)Tt*Bb*Hh*2);   // 256 MB  enc -> h history
  bf16_t* h0b    = (bf16_t*)carve((size_t)Bb*Hh*2);
  bf16_t* enc_wb = (bf16_t*)carve((size_t)Hh*Ii*2);
  bf16_t* rec_wb = (bf16_t*)carve((size_t)Hh*Hh*2);
  bf16_t* dec_wb = (bf16_t*)carve((size_t)Oo*Hh*2);
  unsigned* cnt  = (unsigned*)carve(4*512*4);             // per-(group,step) counters
  if (off > ws_size) return;  // diagnostic: leaves output zeroed

  // reset barrier counters every call (ws is not re-poisoned between replays)
  hipMemsetAsync(cnt, 0, 4*512*4, stream);

  // weights -> bf16
  k_f2b<<<(Hh*Ii)/1024, 256, 0, stream>>>(enc_wb, enc_w);
  k_f2b<<<(Hh*Hh)/1024, 256, 0, stream>>>(rec_wb, rec_w);
  k_f2b<<<(Oo*Hh)/1024, 256, 0, stream>>>(dec_wb, dec_w);
  k_init_h0<<<Hh/256, 256, 0, stream>>>(hi_w, hi_b, h0b);
  k_convert_x<<<((size_t)Tt*Bb*Ii/8)/256, 256, 0, stream>>>(x, x_tm);

  // encoder: EH[t*B+b, h] = x_tm @ enc_w^T + enc_b   (M=65536, K=512, N=2048)
  gemm128<0><<<dim3((Tt*Bb)/128, Hh/128), 256, 0, stream>>>(x_tm, Ii, enc_wb, Ii, enc_b, EH, Hh, Ii);

  // recurrence: one persistent cooperative kernel, 512 steps, 512 threads/block
  {
    float* hfinal = out + (size_t)Tt*Bb*Oo;
    void* args[] = { (void*)&h0b, (void*)&rec_wb, (void*)&EH, (void*)&hfinal,
                     (void*)&rec_b, (void*)&hi_w, (void*)&hi_b, (void*)&dt, (void*)&a,
                     (void*)&cnt };
    hipLaunchCooperativeKernel((const void*)rec_persist, dim3(REC_GRID), dim3(512), args, 0, stream);
  }

  // decoder: out[t*B+b, o] = EH @ dec_w^T + dec_b   (M=65536, K=2048, N=512)
  gemm128<1><<<dim3((Tt*Bb)/128, Oo/128), 256, 0, stream>>>(EH, Hh, dec_wb, Hh, dec_b, out, Oo, Hh);
}